// Round 10
// baseline (964.173 us; speedup 1.0000x reference)
//
#include <hip/hip_runtime.h>
#include <hip/hip_bf16.h>
#include <hip/hip_fp16.h>

#define STEP 0.01f
#define D 64
#define NUM_LAYERS 10

union H4 { uint2 u; __half h[4]; };
union H8 { uint4 u; __half2 h2[4]; __half h[8]; };
union HI { __half2 h; int i; };

typedef float f32x2 __attribute__((ext_vector_type(2)));

// ---------------- CSR build ----------------

__global__ void k_setup(float* __restrict__ degf, int* __restrict__ degd, int N) {
    int n = blockIdx.x * blockDim.x + threadIdx.x;
    if (n < N) { degf[n] = 1.0f; degd[n] = 0; }
}

__global__ void k_deg2(const int* __restrict__ ei, float* __restrict__ degf,
                       int* __restrict__ degd, int E) {
    int e = blockIdx.x * blockDim.x + threadIdx.x;
    if (e < E) {
        unsafeAtomicAdd(&degf[ei[e]], 1.0f);   // out-degree (src)
        atomicAdd(&degd[ei[E + e]], 1);        // in-degree (dst)
    }
}

__global__ __launch_bounds__(1024) void k_scan(
        const int* __restrict__ degd, const float* __restrict__ degf,
        int* __restrict__ row_ptr, int* __restrict__ cursor,
        float* __restrict__ invdeg, int N, int E) {
    __shared__ int part[1024];
    int tid = threadIdx.x;
    int chunk = (N + 1023) / 1024;
    int lo = tid * chunk, hi = min(lo + chunk, N);
    int s = 0;
    for (int i = lo; i < hi; ++i) s += degd[i];
    part[tid] = s;
    __syncthreads();
    for (int off = 1; off < 1024; off <<= 1) {
        int v = (tid >= off) ? part[tid - off] : 0;
        __syncthreads();
        part[tid] += v;
        __syncthreads();
    }
    int base = (tid == 0) ? 0 : part[tid - 1];
    for (int i = lo; i < hi; ++i) {
        row_ptr[i] = base;
        cursor[i] = base;
        base += degd[i];
        invdeg[i] = 1.0f / degf[i];
    }
    if (tid == 1023) row_ptr[N] = E;
}

__global__ void k_scatter(const int* __restrict__ ei, int* __restrict__ cursor,
                          int* __restrict__ col, int E) {
    int e = blockIdx.x * blockDim.x + threadIdx.x;
    if (e < E) {
        int pos = atomicAdd(&cursor[ei[E + e]], 1);
        col[pos] = ei[e];
    }
}

// ---------------- v-recursion precompute (graph-only, one pass per layer) ----------------
// w holds pre-weighted v (v_l * invdeg); vt = sum over in-edges + self;
// rvt = 1/vt (used by layer l); wn = vt * invdeg (next layer's w).

__global__ void k_vmix(const int* __restrict__ row_ptr, const int* __restrict__ col,
                       const float* __restrict__ invdeg, const float* __restrict__ w,
                       float* __restrict__ wn, float* __restrict__ rvt, int N) {
    int n = blockIdx.x * blockDim.x + threadIdx.x;
    if (n < N) {
        int rs = row_ptr[n], re = row_ptr[n + 1];
        float s = w[n];
        for (int e = rs; e < re; ++e) s += w[col[e]];
        rvt[n] = 1.0f / s;
        wn[n] = s * invdeg[n];
    }
}

// ---------------- init: A->fp8 + y=2Ax+b (fp32 exact) + emit pre-weighted fp16 msgs ----------------

__global__ __launch_bounds__(256) void k_init(
        const float* __restrict__ A, const float* __restrict__ b,
        const float* __restrict__ x, const float* __restrict__ invdeg,
        unsigned char* __restrict__ Ah8, __half2* __restrict__ msg,
        float* __restrict__ x0, int N) {
    __shared__ __align__(16) float sx[D];
    __shared__ float syv[D];
    int n = blockIdx.x, t = threadIdx.x;
    int lane = t & 63, w = t >> 6, colgrp = lane & 15;
    if (t < D) sx[t] = x[(size_t)n * D + t];
    __syncthreads();
    const float* An = A + (size_t)n * D * D;
    unsigned char* A8n = Ah8 + (size_t)n * D * D;   // 1 byte/elem, row stride D
    float4 xr = ((const float4*)sx)[colgrp];
    int rbase = w * 16 + (lane >> 4);
#pragma unroll
    for (int g = 0; g < 4; ++g) {
        int row = rbase + g * 4;
        float4 a = ((const float4*)(An + (size_t)row * D))[colgrp];
        // pack 4 floats -> 4 fp8 bytes (RNE, e4m3)
        int d8 = __builtin_amdgcn_cvt_pk_fp8_f32(a.x, a.y, 0, false);
        d8 = __builtin_amdgcn_cvt_pk_fp8_f32(a.z, a.w, d8, true);
        ((unsigned int*)(A8n + (size_t)row * D))[colgrp] = (unsigned int)d8;
        float p = a.x * xr.x + a.y * xr.y + a.z * xr.z + a.w * xr.w;
        p += __shfl_xor(p, 1);
        p += __shfl_xor(p, 2);
        p += __shfl_xor(p, 4);
        p += __shfl_xor(p, 8);
        if (colgrp == 0) syv[row] = 2.0f * p + b[(size_t)n * D + row];
    }
    __syncthreads();
    if (t < D) {
        float wd = invdeg[n];
        float xv = sx[t];
        float yv = syv[t];
        msg[(size_t)n * D + t] = __floats2half2_rn((xv - STEP * yv) * wd, yv * wd);
        x0[(size_t)n * D + t] = xv;
    }
}

// ---------------- fused layer (v6: R9 minus all v machinery; rvt precomputed) ----------------

__global__ __launch_bounds__(256) void k_layer(
        const unsigned char* __restrict__ Ah8,
        const int* __restrict__ row_ptr, const int* __restrict__ col,
        const __half2* __restrict__ msg, const float* __restrict__ rvt,
        const float* __restrict__ invdeg,
        __half2* __restrict__ msgn,
        float* __restrict__ x0, float* __restrict__ xout,
        int last_idx, float comm, int N) {
    __shared__ float su[4][D];
    __shared__ float sy[4][D];
    __shared__ __align__(16) float sdx[D];
    __shared__ float sun[D];
    __shared__ float sytot[D];
    __shared__ float syn[D];

    int n = blockIdx.x, t = threadIdx.x;
    int lane = t & 63, w = t >> 6;
    int j = lane >> 4, q4 = lane & 15;

    // prefetch (independent of the gather; hides under it)
    size_t off = (size_t)n * D + lane;
    float rv = rvt[n];
    float invd = invdeg[n];
    float2 self = {0.f, 0.f};
    float x0v = 0.f;
    if (w == 0) {
        self = __half22float2(msg[off]);
        x0v = x0[off];
    }

    // phase 1: gather — 8 edges per wave-pass (2 per 16-lane group), packed-fp16 accum
    int rs = row_ptr[n], re = row_ptr[n + 1];
    __half2 hz = __floats2half2_rn(0.f, 0.f);
    __half2 ac0 = hz, ac1 = hz, ac2 = hz, ac3 = hz;
    for (int base = rs + w * 8; base < re; base += 32) {
        int e0 = base + (j << 1), e1 = e0 + 1;
        bool b0 = e0 < re, b1 = e1 < re;
        int s0 = 0, s1 = 0;
        if (b0) s0 = col[e0];
        if (b1) s1 = col[e1];
        H8 m0, m1;
        m0.u = make_uint4(0u, 0u, 0u, 0u);
        m1.u = make_uint4(0u, 0u, 0u, 0u);
        if (b0) m0.u = ((const uint4*)(msg + (size_t)s0 * D))[q4];
        if (b1) m1.u = ((const uint4*)(msg + (size_t)s1 * D))[q4];
        ac0 = __hadd2(ac0, m0.h2[0]);
        ac1 = __hadd2(ac1, m0.h2[1]);
        ac2 = __hadd2(ac2, m0.h2[2]);
        ac3 = __hadd2(ac3, m0.h2[3]);
        ac0 = __hadd2(ac0, m1.h2[0]);
        ac1 = __hadd2(ac1, m1.h2[1]);
        ac2 = __hadd2(ac2, m1.h2[2]);
        ac3 = __hadd2(ac3, m1.h2[3]);
    }
    // reduce across the 4 edge groups (lanes xor 16, 32) — packed adds
    {
        HI a, s;
        a.h = ac0; s.i = __shfl_xor(a.i, 16); a.h = __hadd2(a.h, s.h);
        s.i = __shfl_xor(a.i, 32); ac0 = __hadd2(a.h, s.h);
        a.h = ac1; s.i = __shfl_xor(a.i, 16); a.h = __hadd2(a.h, s.h);
        s.i = __shfl_xor(a.i, 32); ac1 = __hadd2(a.h, s.h);
        a.h = ac2; s.i = __shfl_xor(a.i, 16); a.h = __hadd2(a.h, s.h);
        s.i = __shfl_xor(a.i, 32); ac2 = __hadd2(a.h, s.h);
        a.h = ac3; s.i = __shfl_xor(a.i, 16); a.h = __hadd2(a.h, s.h);
        s.i = __shfl_xor(a.i, 32); ac3 = __hadd2(a.h, s.h);
    }
    if (j == 0) {
        float2 f0 = __half22float2(ac0);
        float2 f1 = __half22float2(ac1);
        float2 f2 = __half22float2(ac2);
        float2 f3 = __half22float2(ac3);
        ((float4*)su[w])[q4] = make_float4(f0.x, f1.x, f2.x, f3.x);
        ((float4*)sy[w])[q4] = make_float4(f0.y, f1.y, f2.y, f3.y);
    }
    __syncthreads();

    // phase 2: combine + self term; x1 = ut * rvt; dx = x1 - x0
    if (w == 0) {
        float ut = su[0][lane] + su[1][lane] + su[2][lane] + su[3][lane] + self.x;
        float yt = sy[0][lane] + sy[1][lane] + sy[2][lane] + sy[3][lane] + self.y;
        float x1 = ut * rv;
        sdx[lane] = x1 - x0v;
        x0[off] = x1;
        if (xout) xout[off] = x1;
        sun[lane] = ut;
        sytot[lane] = yt;
    }
    __syncthreads();

    // phase 3: yn = yt + 2*A@dx  (fp8 A, 4KB/block fully-coalesced loads)
    {
        const uint2* Ahp = (const uint2*)(Ah8 + (size_t)n * D * D);
        int cb = (t & 7) * 8;
        int r0 = t >> 3;
        uint2 a0 = Ahp[t];          // row r0,    cols cb..cb+7 (8 fp8 bytes)
        uint2 a1 = Ahp[256 + t];    // row 32+r0, cols cb..cb+7
        float p0 = 0.0f, p1 = 0.0f;
        f32x2 q;
        q = __builtin_amdgcn_cvt_pk_f32_fp8((int)a0.x, false);
        p0 += q.x * sdx[cb + 0] + q.y * sdx[cb + 1];
        q = __builtin_amdgcn_cvt_pk_f32_fp8((int)a0.x, true);
        p0 += q.x * sdx[cb + 2] + q.y * sdx[cb + 3];
        q = __builtin_amdgcn_cvt_pk_f32_fp8((int)a0.y, false);
        p0 += q.x * sdx[cb + 4] + q.y * sdx[cb + 5];
        q = __builtin_amdgcn_cvt_pk_f32_fp8((int)a0.y, true);
        p0 += q.x * sdx[cb + 6] + q.y * sdx[cb + 7];
        q = __builtin_amdgcn_cvt_pk_f32_fp8((int)a1.x, false);
        p1 += q.x * sdx[cb + 0] + q.y * sdx[cb + 1];
        q = __builtin_amdgcn_cvt_pk_f32_fp8((int)a1.x, true);
        p1 += q.x * sdx[cb + 2] + q.y * sdx[cb + 3];
        q = __builtin_amdgcn_cvt_pk_f32_fp8((int)a1.y, false);
        p1 += q.x * sdx[cb + 4] + q.y * sdx[cb + 5];
        q = __builtin_amdgcn_cvt_pk_f32_fp8((int)a1.y, true);
        p1 += q.x * sdx[cb + 6] + q.y * sdx[cb + 7];
        p0 += __shfl_xor(p0, 1); p1 += __shfl_xor(p1, 1);
        p0 += __shfl_xor(p0, 2); p1 += __shfl_xor(p1, 2);
        p0 += __shfl_xor(p0, 4); p1 += __shfl_xor(p1, 4);
        if ((lane & 7) == 0) {
            syn[r0]      = sytot[r0]      + 2.0f * p0;
            syn[32 + r0] = sytot[32 + r0] + 2.0f * p1;
        }
    }
    __syncthreads();

    // phase 4: emit next layer's pre-weighted fp16 messages
    if (t < D) {
        float ynf = syn[t];
        msgn[(size_t)n * D + t] = __floats2half2_rn((sun[t] - STEP * ynf) * invd, ynf * invd);
    }
    if (xout && n == 0 && t == 0) xout[last_idx] = comm;
}

// ---------------- host launcher ----------------

extern "C" void kernel_launch(void* const* d_in, const int* in_sizes, int n_in,
                              void* d_out, int out_size, void* d_ws, size_t ws_size,
                              hipStream_t stream) {
    const float* A  = (const float*)d_in[0];
    const float* b  = (const float*)d_in[1];
    const float* x  = (const float*)d_in[2];
    const int*   ei = (const int*)d_in[3];

    const int N = in_sizes[1] / D;        // b is [N, D]
    const int E = in_sizes[3] / 2;        // edge_index is [2, E]
    const size_t ND = (size_t)N * D;

    char* ws = (char*)d_ws;
    unsigned char* Ah8 = (unsigned char*)ws;                // N*D*D bytes (fp8)
    __half2* msg0 = (__half2*)(ws + ND * D);
    __half2* msg1 = msg0 + ND;
    float* x0   = (float*)(msg1 + ND);
    float* vw0  = x0 + ND;
    float* vw1  = vw0 + N;
    float* invdeg = vw1 + N;
    float* degf = invdeg + N;
    int* degd    = (int*)(degf + N);
    int* row_ptr = degd + N;
    int* cursor  = row_ptr + N + 4;
    int* col     = cursor + N;
    float* rvtbuf = (float*)(col + E);    // [NUM_LAYERS][N]

    k_setup<<<(N + 255) / 256, 256, 0, stream>>>(degf, degd, N);
    k_deg2<<<(E + 255) / 256, 256, 0, stream>>>(ei, degf, degd, E);
    k_scan<<<1, 1024, 0, stream>>>(degd, degf, row_ptr, cursor, invdeg, N, E);
    k_scatter<<<(E + 255) / 256, 256, 0, stream>>>(ei, cursor, col, E);

    // v-recursion precompute: w_0 = invdeg; rvt[l] = 1/vt_l; w ping-pongs vw0/vw1
    {
        const float* wcur = invdeg;
        float* wnxt = vw0;
        for (int l = 0; l < NUM_LAYERS; ++l) {
            k_vmix<<<(N + 255) / 256, 256, 0, stream>>>(
                row_ptr, col, invdeg, wcur, wnxt, rvtbuf + (size_t)l * N, N);
            const float* tw = wnxt;
            wnxt = (wnxt == vw0) ? vw1 : vw0;
            wcur = tw;
        }
    }

    k_init<<<N, 256, 0, stream>>>(A, b, x, invdeg, Ah8, msg0, x0, N);

    float comm = (float)(3 * NUM_LAYERS * E);
    __half2 *mc = msg0, *mn = msg1;
    for (int l = 0; l < NUM_LAYERS; ++l) {
        float* xout = (l == NUM_LAYERS - 1) ? (float*)d_out : nullptr;
        k_layer<<<N, 256, 0, stream>>>(Ah8, row_ptr, col, mc, rvtbuf + (size_t)l * N,
                                       invdeg, mn, x0, xout, out_size - 1, comm, N);
        __half2* tm = mc; mc = mn; mn = tm;
    }
}

// Round 11
// 960.211 us; speedup vs baseline: 1.0041x; 1.0041x over previous
//
#include <hip/hip_runtime.h>
#include <hip/hip_bf16.h>
#include <hip/hip_fp16.h>

#define STEP 0.01f
#define D 64
#define NUM_LAYERS 10

union H4 { uint2 u; __half h[4]; };
union H8 { uint4 u; __half2 h2[4]; __half h[8]; };
union HI { __half2 h; int i; };

typedef float f32x2 __attribute__((ext_vector_type(2)));

// ---------------- CSR build ----------------

__global__ void k_setup(float* __restrict__ degf, int* __restrict__ degd, int N) {
    int n = blockIdx.x * blockDim.x + threadIdx.x;
    if (n < N) { degf[n] = 1.0f; degd[n] = 0; }
}

__global__ void k_deg2(const int* __restrict__ ei, float* __restrict__ degf,
                       int* __restrict__ degd, int E) {
    int e = blockIdx.x * blockDim.x + threadIdx.x;
    if (e < E) {
        unsafeAtomicAdd(&degf[ei[e]], 1.0f);   // out-degree (src)
        atomicAdd(&degd[ei[E + e]], 1);        // in-degree (dst)
    }
}

__global__ __launch_bounds__(1024) void k_scan(
        const int* __restrict__ degd, const float* __restrict__ degf,
        int* __restrict__ row_ptr, int* __restrict__ cursor,
        float* __restrict__ invdeg, int N, int E) {
    __shared__ int part[1024];
    int tid = threadIdx.x;
    int chunk = (N + 1023) / 1024;
    int lo = tid * chunk, hi = min(lo + chunk, N);
    int s = 0;
    for (int i = lo; i < hi; ++i) s += degd[i];
    part[tid] = s;
    __syncthreads();
    for (int off = 1; off < 1024; off <<= 1) {
        int v = (tid >= off) ? part[tid - off] : 0;
        __syncthreads();
        part[tid] += v;
        __syncthreads();
    }
    int base = (tid == 0) ? 0 : part[tid - 1];
    for (int i = lo; i < hi; ++i) {
        row_ptr[i] = base;
        cursor[i] = base;
        base += degd[i];
        invdeg[i] = 1.0f / degf[i];
    }
    if (tid == 1023) row_ptr[N] = E;
}

__global__ void k_scatter(const int* __restrict__ ei, int* __restrict__ cursor,
                          int* __restrict__ col, int E) {
    int e = blockIdx.x * blockDim.x + threadIdx.x;
    if (e < E) {
        int pos = atomicAdd(&cursor[ei[E + e]], 1);
        col[pos] = ei[e];
    }
}

// ---------------- init: A->fp8 + y=2Ax+b (fp32 exact) + emit pre-weighted fp16 msgs ----------------

__global__ __launch_bounds__(256) void k_init(
        const float* __restrict__ A, const float* __restrict__ b,
        const float* __restrict__ x, const float* __restrict__ invdeg,
        unsigned char* __restrict__ Ah8, __half2* __restrict__ msg,
        float* __restrict__ vw, float* __restrict__ x0, int N) {
    __shared__ __align__(16) float sx[D];
    __shared__ float syv[D];
    int n = blockIdx.x, t = threadIdx.x;
    int lane = t & 63, w = t >> 6, colgrp = lane & 15;
    if (t < D) sx[t] = x[(size_t)n * D + t];
    __syncthreads();
    const float* An = A + (size_t)n * D * D;
    unsigned char* A8n = Ah8 + (size_t)n * D * D;   // 1 byte/elem, row stride D
    float4 xr = ((const float4*)sx)[colgrp];
    int rbase = w * 16 + (lane >> 4);
#pragma unroll
    for (int g = 0; g < 4; ++g) {
        int row = rbase + g * 4;
        float4 a = ((const float4*)(An + (size_t)row * D))[colgrp];
        // pack 4 floats -> 4 fp8 bytes (RNE, e4m3)
        int d8 = __builtin_amdgcn_cvt_pk_fp8_f32(a.x, a.y, 0, false);
        d8 = __builtin_amdgcn_cvt_pk_fp8_f32(a.z, a.w, d8, true);
        ((unsigned int*)(A8n + (size_t)row * D))[colgrp] = (unsigned int)d8;
        float p = a.x * xr.x + a.y * xr.y + a.z * xr.z + a.w * xr.w;
        p += __shfl_xor(p, 1);
        p += __shfl_xor(p, 2);
        p += __shfl_xor(p, 4);
        p += __shfl_xor(p, 8);
        if (colgrp == 0) syv[row] = 2.0f * p + b[(size_t)n * D + row];
    }
    __syncthreads();
    if (t < D) {
        float wd = invdeg[n];
        float xv = sx[t];
        float yv = syv[t];
        msg[(size_t)n * D + t] = __floats2half2_rn((xv - STEP * yv) * wd, yv * wd);
        x0[(size_t)n * D + t] = xv;
        if (t == 0) vw[n] = wd;
    }
}

// ---------------- fused layer (v7: R9 + non-temporal Ah8 stream + pinned occupancy) ----------------

__global__ __launch_bounds__(256, 8) void k_layer(
        const unsigned char* __restrict__ Ah8,
        const int* __restrict__ row_ptr, const int* __restrict__ col,
        const __half2* __restrict__ msg, const float* __restrict__ vw,
        const float* __restrict__ invdeg,
        __half2* __restrict__ msgn, float* __restrict__ vwn,
        float* __restrict__ x0, float* __restrict__ xout,
        int last_idx, float comm, int N) {
    __shared__ float su[4][D];
    __shared__ float sy[4][D];
    __shared__ float sv[4];
    __shared__ __align__(16) float sdx[D];
    __shared__ float sun[D];
    __shared__ float sytot[D];
    __shared__ float syn[D];
    __shared__ float svn;

    int n = blockIdx.x, t = threadIdx.x;
    int lane = t & 63, w = t >> 6;
    int j = lane >> 4, q4 = lane & 15;

    // phase 1: gather — 8 edges per wave-pass (2 per 16-lane group), packed-fp16 accum
    int rs = row_ptr[n], re = row_ptr[n + 1];
    __half2 hz = __floats2half2_rn(0.f, 0.f);
    __half2 ac0 = hz, ac1 = hz, ac2 = hz, ac3 = hz;
    float av = 0.0f;
    for (int base = rs + w * 8; base < re; base += 32) {
        int e0 = base + (j << 1), e1 = e0 + 1;
        bool b0 = e0 < re, b1 = e1 < re;
        int s0 = 0, s1 = 0;
        if (b0) s0 = col[e0];
        if (b1) s1 = col[e1];
        H8 m0, m1;
        m0.u = make_uint4(0u, 0u, 0u, 0u);
        m1.u = make_uint4(0u, 0u, 0u, 0u);
        float w0 = 0.f, w1 = 0.f;
        if (b0) m0.u = ((const uint4*)(msg + (size_t)s0 * D))[q4];
        if (b1) m1.u = ((const uint4*)(msg + (size_t)s1 * D))[q4];
        if (b0 && q4 == 0) w0 = vw[s0];
        if (b1 && q4 == 0) w1 = vw[s1];
        ac0 = __hadd2(ac0, m0.h2[0]);
        ac1 = __hadd2(ac1, m0.h2[1]);
        ac2 = __hadd2(ac2, m0.h2[2]);
        ac3 = __hadd2(ac3, m0.h2[3]);
        ac0 = __hadd2(ac0, m1.h2[0]);
        ac1 = __hadd2(ac1, m1.h2[1]);
        ac2 = __hadd2(ac2, m1.h2[2]);
        ac3 = __hadd2(ac3, m1.h2[3]);
        av += w0 + w1;
    }
    // reduce across the 4 edge groups (lanes xor 16, 32) — packed adds
    {
        HI a, s;
        a.h = ac0; s.i = __shfl_xor(a.i, 16); a.h = __hadd2(a.h, s.h);
        s.i = __shfl_xor(a.i, 32); ac0 = __hadd2(a.h, s.h);
        a.h = ac1; s.i = __shfl_xor(a.i, 16); a.h = __hadd2(a.h, s.h);
        s.i = __shfl_xor(a.i, 32); ac1 = __hadd2(a.h, s.h);
        a.h = ac2; s.i = __shfl_xor(a.i, 16); a.h = __hadd2(a.h, s.h);
        s.i = __shfl_xor(a.i, 32); ac2 = __hadd2(a.h, s.h);
        a.h = ac3; s.i = __shfl_xor(a.i, 16); a.h = __hadd2(a.h, s.h);
        s.i = __shfl_xor(a.i, 32); ac3 = __hadd2(a.h, s.h);
    }
    av += __shfl_xor(av, 16);
    av += __shfl_xor(av, 32);
    if (j == 0) {
        float2 f0 = __half22float2(ac0);
        float2 f1 = __half22float2(ac1);
        float2 f2 = __half22float2(ac2);
        float2 f3 = __half22float2(ac3);
        ((float4*)su[w])[q4] = make_float4(f0.x, f1.x, f2.x, f3.x);
        ((float4*)sy[w])[q4] = make_float4(f0.y, f1.y, f2.y, f3.y);
        if (q4 == 0) sv[w] = av;
    }
    __syncthreads();

    // phase 2: combine + self term; x1 = un/vn; dx = x1 - x0
    if (w == 0) {
        size_t off = (size_t)n * D + lane;
        float2 self = __half22float2(msg[off]);
        float ut = su[0][lane] + su[1][lane] + su[2][lane] + su[3][lane] + self.x;
        float yt = sy[0][lane] + sy[1][lane] + sy[2][lane] + sy[3][lane] + self.y;
        float vt = sv[0] + sv[1] + sv[2] + sv[3] + vw[n];
        float x1 = ut / vt;
        sdx[lane] = x1 - x0[off];
        x0[off] = x1;
        if (xout) xout[off] = x1;
        sun[lane] = ut;
        sytot[lane] = yt;
        if (lane == 0) svn = vt;
    }
    __syncthreads();

    // phase 3: yn = yt + 2*A@dx  (fp8 A, non-temporal loads: single-use stream,
    // keep it out of L2 so the reused msg lines stay resident)
    {
        const unsigned long long* Ahp =
            (const unsigned long long*)(Ah8 + (size_t)n * D * D);
        int cb = (t & 7) * 8;
        int r0 = t >> 3;
        unsigned long long v0 = __builtin_nontemporal_load(Ahp + t);        // row r0
        unsigned long long v1 = __builtin_nontemporal_load(Ahp + 256 + t);  // row 32+r0
        unsigned int a0x = (unsigned int)v0, a0y = (unsigned int)(v0 >> 32);
        unsigned int a1x = (unsigned int)v1, a1y = (unsigned int)(v1 >> 32);
        float p0 = 0.0f, p1 = 0.0f;
        f32x2 q;
        q = __builtin_amdgcn_cvt_pk_f32_fp8((int)a0x, false);
        p0 += q.x * sdx[cb + 0] + q.y * sdx[cb + 1];
        q = __builtin_amdgcn_cvt_pk_f32_fp8((int)a0x, true);
        p0 += q.x * sdx[cb + 2] + q.y * sdx[cb + 3];
        q = __builtin_amdgcn_cvt_pk_f32_fp8((int)a0y, false);
        p0 += q.x * sdx[cb + 4] + q.y * sdx[cb + 5];
        q = __builtin_amdgcn_cvt_pk_f32_fp8((int)a0y, true);
        p0 += q.x * sdx[cb + 6] + q.y * sdx[cb + 7];
        q = __builtin_amdgcn_cvt_pk_f32_fp8((int)a1x, false);
        p1 += q.x * sdx[cb + 0] + q.y * sdx[cb + 1];
        q = __builtin_amdgcn_cvt_pk_f32_fp8((int)a1x, true);
        p1 += q.x * sdx[cb + 2] + q.y * sdx[cb + 3];
        q = __builtin_amdgcn_cvt_pk_f32_fp8((int)a1y, false);
        p1 += q.x * sdx[cb + 4] + q.y * sdx[cb + 5];
        q = __builtin_amdgcn_cvt_pk_f32_fp8((int)a1y, true);
        p1 += q.x * sdx[cb + 6] + q.y * sdx[cb + 7];
        p0 += __shfl_xor(p0, 1); p1 += __shfl_xor(p1, 1);
        p0 += __shfl_xor(p0, 2); p1 += __shfl_xor(p1, 2);
        p0 += __shfl_xor(p0, 4); p1 += __shfl_xor(p1, 4);
        if ((lane & 7) == 0) {
            syn[r0]      = sytot[r0]      + 2.0f * p0;
            syn[32 + r0] = sytot[32 + r0] + 2.0f * p1;
        }
    }
    __syncthreads();

    // phase 4: emit next layer's pre-weighted fp16 messages
    if (t < D) {
        float wd = invdeg[n];
        float ynf = syn[t];
        msgn[(size_t)n * D + t] = __floats2half2_rn((sun[t] - STEP * ynf) * wd, ynf * wd);
        if (t == 0) vwn[n] = svn * wd;
    }
    if (xout && n == 0 && t == 0) xout[last_idx] = comm;
}

// ---------------- host launcher ----------------

extern "C" void kernel_launch(void* const* d_in, const int* in_sizes, int n_in,
                              void* d_out, int out_size, void* d_ws, size_t ws_size,
                              hipStream_t stream) {
    const float* A  = (const float*)d_in[0];
    const float* b  = (const float*)d_in[1];
    const float* x  = (const float*)d_in[2];
    const int*   ei = (const int*)d_in[3];

    const int N = in_sizes[1] / D;        // b is [N, D]
    const int E = in_sizes[3] / 2;        // edge_index is [2, E]
    const size_t ND = (size_t)N * D;

    char* ws = (char*)d_ws;
    unsigned char* Ah8 = (unsigned char*)ws;                // N*D*D bytes (fp8)
    __half2* msg0 = (__half2*)(ws + ND * D);
    __half2* msg1 = msg0 + ND;
    float* x0   = (float*)(msg1 + ND);
    float* vw0  = x0 + ND;
    float* vw1  = vw0 + N;
    float* invdeg = vw1 + N;
    float* degf = invdeg + N;
    int* degd    = (int*)(degf + N);
    int* row_ptr = degd + N;
    int* cursor  = row_ptr + N + 4;
    int* col     = cursor + N;

    k_setup<<<(N + 255) / 256, 256, 0, stream>>>(degf, degd, N);
    k_deg2<<<(E + 255) / 256, 256, 0, stream>>>(ei, degf, degd, E);
    k_scan<<<1, 1024, 0, stream>>>(degd, degf, row_ptr, cursor, invdeg, N, E);
    k_scatter<<<(E + 255) / 256, 256, 0, stream>>>(ei, cursor, col, E);
    k_init<<<N, 256, 0, stream>>>(A, b, x, invdeg, Ah8, msg0, vw0, x0, N);

    float comm = (float)(3 * NUM_LAYERS * E);
    __half2 *mc = msg0, *mn = msg1;
    float *vc = vw0, *vn = vw1;
    for (int l = 0; l < NUM_LAYERS; ++l) {
        float* xout = (l == NUM_LAYERS - 1) ? (float*)d_out : nullptr;
        k_layer<<<N, 256, 0, stream>>>(Ah8, row_ptr, col, mc, vc, invdeg,
                                       mn, vn, x0, xout, out_size - 1, comm, N);
        __half2* tm = mc; mc = mn; mn = tm;
        float* tv = vc; vc = vn; vn = tv;
    }
}

// Round 12
// 909.443 us; speedup vs baseline: 1.0602x; 1.0558x over previous
//
#include <hip/hip_runtime.h>
#include <hip/hip_bf16.h>
#include <hip/hip_fp16.h>

#define STEP 0.01f
#define D 64
#define NUM_LAYERS 10

union H4 { uint2 u; __half h[4]; };
union H8 { uint4 u; __half2 h2[4]; __half h[8]; };
union HI { __half2 h; int i; };

typedef float f32x2 __attribute__((ext_vector_type(2)));

// ---------------- CSR build ----------------

__global__ void k_setup(float* __restrict__ degf, int* __restrict__ degd, int N) {
    int n = blockIdx.x * blockDim.x + threadIdx.x;
    if (n < N) { degf[n] = 1.0f; degd[n] = 0; }
}

__global__ void k_deg2(const int* __restrict__ ei, float* __restrict__ degf,
                       int* __restrict__ degd, int E) {
    int e = blockIdx.x * blockDim.x + threadIdx.x;
    if (e < E) {
        unsafeAtomicAdd(&degf[ei[e]], 1.0f);   // out-degree (src)
        atomicAdd(&degd[ei[E + e]], 1);        // in-degree (dst)
    }
}

__global__ __launch_bounds__(1024) void k_scan(
        const int* __restrict__ degd, const float* __restrict__ degf,
        int* __restrict__ row_ptr, int* __restrict__ cursor,
        float* __restrict__ invdeg, int N, int E) {
    __shared__ int part[1024];
    int tid = threadIdx.x;
    int chunk = (N + 1023) / 1024;
    int lo = tid * chunk, hi = min(lo + chunk, N);
    int s = 0;
    for (int i = lo; i < hi; ++i) s += degd[i];
    part[tid] = s;
    __syncthreads();
    for (int off = 1; off < 1024; off <<= 1) {
        int v = (tid >= off) ? part[tid - off] : 0;
        __syncthreads();
        part[tid] += v;
        __syncthreads();
    }
    int base = (tid == 0) ? 0 : part[tid - 1];
    for (int i = lo; i < hi; ++i) {
        row_ptr[i] = base;
        cursor[i] = base;
        base += degd[i];
        invdeg[i] = 1.0f / degf[i];
    }
    if (tid == 1023) row_ptr[N] = E;
}

__global__ void k_scatter(const int* __restrict__ ei, int* __restrict__ cursor,
                          int* __restrict__ col, int E) {
    int e = blockIdx.x * blockDim.x + threadIdx.x;
    if (e < E) {
        int pos = atomicAdd(&cursor[ei[E + e]], 1);
        col[pos] = ei[e];
    }
}

// ---------------- init: A->fp8 + y=2Ax+b (fp32 exact) + emit pre-weighted fp16 msgs ----------------

__global__ __launch_bounds__(256) void k_init(
        const float* __restrict__ A, const float* __restrict__ b,
        const float* __restrict__ x, const float* __restrict__ invdeg,
        unsigned char* __restrict__ Ah8, __half2* __restrict__ msg,
        float* __restrict__ vw, float* __restrict__ x0, int N) {
    __shared__ __align__(16) float sx[D];
    __shared__ float syv[D];
    int n = blockIdx.x, t = threadIdx.x;
    int lane = t & 63, w = t >> 6, colgrp = lane & 15;
    if (t < D) sx[t] = x[(size_t)n * D + t];
    __syncthreads();
    const float* An = A + (size_t)n * D * D;
    unsigned char* A8n = Ah8 + (size_t)n * D * D;   // 1 byte/elem, row stride D
    float4 xr = ((const float4*)sx)[colgrp];
    int rbase = w * 16 + (lane >> 4);
#pragma unroll
    for (int g = 0; g < 4; ++g) {
        int row = rbase + g * 4;
        float4 a = ((const float4*)(An + (size_t)row * D))[colgrp];
        // pack 4 floats -> 4 fp8 bytes (RNE, e4m3)
        int d8 = __builtin_amdgcn_cvt_pk_fp8_f32(a.x, a.y, 0, false);
        d8 = __builtin_amdgcn_cvt_pk_fp8_f32(a.z, a.w, d8, true);
        ((unsigned int*)(A8n + (size_t)row * D))[colgrp] = (unsigned int)d8;
        float p = a.x * xr.x + a.y * xr.y + a.z * xr.z + a.w * xr.w;
        p += __shfl_xor(p, 1);
        p += __shfl_xor(p, 2);
        p += __shfl_xor(p, 4);
        p += __shfl_xor(p, 8);
        if (colgrp == 0) syv[row] = 2.0f * p + b[(size_t)n * D + row];
    }
    __syncthreads();
    if (t < D) {
        float wd = invdeg[n];
        float xv = sx[t];
        float yv = syv[t];
        msg[(size_t)n * D + t] = __floats2half2_rn((xv - STEP * yv) * wd, yv * wd);
        x0[(size_t)n * D + t] = xv;
        if (t == 0) vw[n] = wd;
    }
}

// ---------------- fused layer (v5 = R9 best: 32-edge single-pass gather, fp16 accum, fp8 matvec) ----------------

__global__ __launch_bounds__(256) void k_layer(
        const unsigned char* __restrict__ Ah8,
        const int* __restrict__ row_ptr, const int* __restrict__ col,
        const __half2* __restrict__ msg, const float* __restrict__ vw,
        const float* __restrict__ invdeg,
        __half2* __restrict__ msgn, float* __restrict__ vwn,
        float* __restrict__ x0, float* __restrict__ xout,
        int last_idx, float comm, int N) {
    __shared__ float su[4][D];
    __shared__ float sy[4][D];
    __shared__ float sv[4];
    __shared__ __align__(16) float sdx[D];
    __shared__ float sun[D];
    __shared__ float sytot[D];
    __shared__ float syn[D];
    __shared__ float svn;

    int n = blockIdx.x, t = threadIdx.x;
    int lane = t & 63, w = t >> 6;
    int j = lane >> 4, q4 = lane & 15;

    // phase 1: gather — 8 edges per wave-pass (2 per 16-lane group), packed-fp16 accum
    int rs = row_ptr[n], re = row_ptr[n + 1];
    __half2 hz = __floats2half2_rn(0.f, 0.f);
    __half2 ac0 = hz, ac1 = hz, ac2 = hz, ac3 = hz;
    float av = 0.0f;
    for (int base = rs + w * 8; base < re; base += 32) {
        int e0 = base + (j << 1), e1 = e0 + 1;
        bool b0 = e0 < re, b1 = e1 < re;
        int s0 = 0, s1 = 0;
        if (b0) s0 = col[e0];
        if (b1) s1 = col[e1];
        H8 m0, m1;
        m0.u = make_uint4(0u, 0u, 0u, 0u);
        m1.u = make_uint4(0u, 0u, 0u, 0u);
        float w0 = 0.f, w1 = 0.f;
        if (b0) m0.u = ((const uint4*)(msg + (size_t)s0 * D))[q4];
        if (b1) m1.u = ((const uint4*)(msg + (size_t)s1 * D))[q4];
        if (b0 && q4 == 0) w0 = vw[s0];
        if (b1 && q4 == 0) w1 = vw[s1];
        ac0 = __hadd2(ac0, m0.h2[0]);
        ac1 = __hadd2(ac1, m0.h2[1]);
        ac2 = __hadd2(ac2, m0.h2[2]);
        ac3 = __hadd2(ac3, m0.h2[3]);
        ac0 = __hadd2(ac0, m1.h2[0]);
        ac1 = __hadd2(ac1, m1.h2[1]);
        ac2 = __hadd2(ac2, m1.h2[2]);
        ac3 = __hadd2(ac3, m1.h2[3]);
        av += w0 + w1;
    }
    // reduce across the 4 edge groups (lanes xor 16, 32) — packed adds
    {
        HI a, s;
        a.h = ac0; s.i = __shfl_xor(a.i, 16); a.h = __hadd2(a.h, s.h);
        s.i = __shfl_xor(a.i, 32); ac0 = __hadd2(a.h, s.h);
        a.h = ac1; s.i = __shfl_xor(a.i, 16); a.h = __hadd2(a.h, s.h);
        s.i = __shfl_xor(a.i, 32); ac1 = __hadd2(a.h, s.h);
        a.h = ac2; s.i = __shfl_xor(a.i, 16); a.h = __hadd2(a.h, s.h);
        s.i = __shfl_xor(a.i, 32); ac2 = __hadd2(a.h, s.h);
        a.h = ac3; s.i = __shfl_xor(a.i, 16); a.h = __hadd2(a.h, s.h);
        s.i = __shfl_xor(a.i, 32); ac3 = __hadd2(a.h, s.h);
    }
    av += __shfl_xor(av, 16);
    av += __shfl_xor(av, 32);
    if (j == 0) {
        float2 f0 = __half22float2(ac0);
        float2 f1 = __half22float2(ac1);
        float2 f2 = __half22float2(ac2);
        float2 f3 = __half22float2(ac3);
        ((float4*)su[w])[q4] = make_float4(f0.x, f1.x, f2.x, f3.x);
        ((float4*)sy[w])[q4] = make_float4(f0.y, f1.y, f2.y, f3.y);
        if (q4 == 0) sv[w] = av;
    }
    __syncthreads();

    // phase 2: combine + self term; x1 = un/vn; dx = x1 - x0
    if (w == 0) {
        size_t off = (size_t)n * D + lane;
        float2 self = __half22float2(msg[off]);
        float ut = su[0][lane] + su[1][lane] + su[2][lane] + su[3][lane] + self.x;
        float yt = sy[0][lane] + sy[1][lane] + sy[2][lane] + sy[3][lane] + self.y;
        float vt = sv[0] + sv[1] + sv[2] + sv[3] + vw[n];
        float x1 = ut / vt;
        sdx[lane] = x1 - x0[off];
        x0[off] = x1;
        if (xout) xout[off] = x1;
        sun[lane] = ut;
        sytot[lane] = yt;
        if (lane == 0) svn = vt;
    }
    __syncthreads();

    // phase 3: yn = yt + 2*A@dx  (fp8 A, 4KB/block fully-coalesced loads)
    {
        const uint2* Ahp = (const uint2*)(Ah8 + (size_t)n * D * D);
        int cb = (t & 7) * 8;
        int r0 = t >> 3;
        uint2 a0 = Ahp[t];          // row r0,    cols cb..cb+7 (8 fp8 bytes)
        uint2 a1 = Ahp[256 + t];    // row 32+r0, cols cb..cb+7
        float p0 = 0.0f, p1 = 0.0f;
        f32x2 q;
        q = __builtin_amdgcn_cvt_pk_f32_fp8((int)a0.x, false);
        p0 += q.x * sdx[cb + 0] + q.y * sdx[cb + 1];
        q = __builtin_amdgcn_cvt_pk_f32_fp8((int)a0.x, true);
        p0 += q.x * sdx[cb + 2] + q.y * sdx[cb + 3];
        q = __builtin_amdgcn_cvt_pk_f32_fp8((int)a0.y, false);
        p0 += q.x * sdx[cb + 4] + q.y * sdx[cb + 5];
        q = __builtin_amdgcn_cvt_pk_f32_fp8((int)a0.y, true);
        p0 += q.x * sdx[cb + 6] + q.y * sdx[cb + 7];
        q = __builtin_amdgcn_cvt_pk_f32_fp8((int)a1.x, false);
        p1 += q.x * sdx[cb + 0] + q.y * sdx[cb + 1];
        q = __builtin_amdgcn_cvt_pk_f32_fp8((int)a1.x, true);
        p1 += q.x * sdx[cb + 2] + q.y * sdx[cb + 3];
        q = __builtin_amdgcn_cvt_pk_f32_fp8((int)a1.y, false);
        p1 += q.x * sdx[cb + 4] + q.y * sdx[cb + 5];
        q = __builtin_amdgcn_cvt_pk_f32_fp8((int)a1.y, true);
        p1 += q.x * sdx[cb + 6] + q.y * sdx[cb + 7];
        p0 += __shfl_xor(p0, 1); p1 += __shfl_xor(p1, 1);
        p0 += __shfl_xor(p0, 2); p1 += __shfl_xor(p1, 2);
        p0 += __shfl_xor(p0, 4); p1 += __shfl_xor(p1, 4);
        if ((lane & 7) == 0) {
            syn[r0]      = sytot[r0]      + 2.0f * p0;
            syn[32 + r0] = sytot[32 + r0] + 2.0f * p1;
        }
    }
    __syncthreads();

    // phase 4: emit next layer's pre-weighted fp16 messages
    if (t < D) {
        float wd = invdeg[n];
        float ynf = syn[t];
        msgn[(size_t)n * D + t] = __floats2half2_rn((sun[t] - STEP * ynf) * wd, ynf * wd);
        if (t == 0) vwn[n] = svn * wd;
    }
    if (xout && n == 0 && t == 0) xout[last_idx] = comm;
}

// ---------------- host launcher ----------------

extern "C" void kernel_launch(void* const* d_in, const int* in_sizes, int n_in,
                              void* d_out, int out_size, void* d_ws, size_t ws_size,
                              hipStream_t stream) {
    const float* A  = (const float*)d_in[0];
    const float* b  = (const float*)d_in[1];
    const float* x  = (const float*)d_in[2];
    const int*   ei = (const int*)d_in[3];

    const int N = in_sizes[1] / D;        // b is [N, D]
    const int E = in_sizes[3] / 2;        // edge_index is [2, E]
    const size_t ND = (size_t)N * D;

    char* ws = (char*)d_ws;
    unsigned char* Ah8 = (unsigned char*)ws;                // N*D*D bytes (fp8)
    __half2* msg0 = (__half2*)(ws + ND * D);
    __half2* msg1 = msg0 + ND;
    float* x0   = (float*)(msg1 + ND);
    float* vw0  = x0 + ND;
    float* vw1  = vw0 + N;
    float* invdeg = vw1 + N;
    float* degf = invdeg + N;
    int* degd    = (int*)(degf + N);
    int* row_ptr = degd + N;
    int* cursor  = row_ptr + N + 4;
    int* col     = cursor + N;

    k_setup<<<(N + 255) / 256, 256, 0, stream>>>(degf, degd, N);
    k_deg2<<<(E + 255) / 256, 256, 0, stream>>>(ei, degf, degd, E);
    k_scan<<<1, 1024, 0, stream>>>(degd, degf, row_ptr, cursor, invdeg, N, E);
    k_scatter<<<(E + 255) / 256, 256, 0, stream>>>(ei, cursor, col, E);
    k_init<<<N, 256, 0, stream>>>(A, b, x, invdeg, Ah8, msg0, vw0, x0, N);

    float comm = (float)(3 * NUM_LAYERS * E);
    __half2 *mc = msg0, *mn = msg1;
    float *vc = vw0, *vn = vw1;
    for (int l = 0; l < NUM_LAYERS; ++l) {
        float* xout = (l == NUM_LAYERS - 1) ? (float*)d_out : nullptr;
        k_layer<<<N, 256, 0, stream>>>(Ah8, row_ptr, col, mc, vc, invdeg,
                                       mn, vn, x0, xout, out_size - 1, comm, N);
        __half2* tm = mc; mc = mn; mn = tm;
        float* tv = vc; vc = vn; vn = tv;
    }
}